// Round 13
// baseline (257.390 us; speedup 1.0000x reference)
//
#include <hip/hip_runtime.h>
#include <hip/hip_bf16.h>

#define N_ 256
#define C_ 128
#define S_ 961
#define K_ 64
#define TS 64
#define NTILE_LOC 8
#define NTHREADS 512

typedef __attribute__((ext_vector_type(4))) float f32x4;
typedef __attribute__((ext_vector_type(8))) _Float16 f16x8;
typedef __attribute__((ext_vector_type(4))) _Float16 f16x4;

#define MFMAF(a, b, c) __builtin_amdgcn_mfma_f32_16x16x32_f16((a), (b), (c), 0, 0, 0)

// MODE 0: partials to out/ws (separate norm kernel)   MODE 1: fused last-block finish
// MODE 2: atomicAdd into out (separate norm kernel)
template <int MODE>
__global__ __launch_bounds__(NTHREADS, 8) void vlad_main(
    const float* __restrict__ x,       // [N,C,S]
    const float* __restrict__ conv_w,  // [K,C]
    const float* __restrict__ cent,    // [K,C]
    const float* __restrict__ aw,      // [C]
    const float* __restrict__ ab,      // [1]
    float* __restrict__ out,
    float* __restrict__ ws,
    int* __restrict__ cnt)
{
    __shared__ _Float16 s_xs[C_][72];      // [c][s] pitch 144B
    __shared__ __align__(16) unsigned char s_xtu[TS * 136 * sizeof(_Float16)];
    _Float16 (*s_xT)[136] = (_Float16 (*)[136])s_xtu;  // stage->GEMM1
    _Float16 (*s_u)[72]   = (_Float16 (*)[72])s_xtu;   // softmax->GEMM2
    __shared__ _Float16 s_cw[16][64][8];   // conv_w fragments
    __shared__ float s_ared[2][8][68];
    __shared__ float s_cs[8][68];
    __shared__ float s_wp[8][4][8];
    __shared__ float s_wsum[K_];
    __shared__ float s_fin;
    __shared__ int s_flag;

    const int tid = threadIdx.x;
    const int bid = blockIdx.x;
    const int n = bid >> 1, h = bid & 1;
    const int sbase = h * (NTILE_LOC * TS);
    const int lane = tid & 63;
    const int w = tid >> 6;
    const int la = lane & 15;
    const int lg = lane >> 4;
    const float bias = ab[0];
    const float* xn = x + (size_t)n * (C_ * S_);

    const int cb = tid >> 4;
    const int c0 = cb * 4;
    const int s0l = (tid & 15) * 4;

    float awr[4];
    #pragma unroll
    for (int r = 0; r < 4; ++r) awr[r] = aw[c0 + r];

    // ---- stage conv_w fragments into LDS (once) ----
    {
        int b = tid >> 5;
        int mt = b >> 2, cc = b & 3;
        #pragma unroll
        for (int dl = 0; dl < 2; ++dl) {
            int l = (tid & 31) * 2 + dl;
            const float* p = conv_w + ((l & 15) + 16 * mt) * C_ + 8 * (l >> 4) + 32 * cc;
            f16x8 v;
            #pragma unroll
            for (int i = 0; i < 8; ++i) v[i] = (_Float16)p[i];
            *(f16x8*)&s_cw[b][l][0] = v;
        }
    }

    const int nt1 = w & 3;
    const int mtb = (w >> 2) * 2;
    const int sc = 16 * nt1 + la;

    const int mtb2 = (w & 1) * 2;
    const int ctb2 = (w >> 1) * 2;
    f32x4 acc2[2][2];
    #pragma unroll
    for (int m = 0; m < 2; ++m)
        #pragma unroll
        for (int ci = 0; ci < 2; ++ci) acc2[m][ci] = (f32x4){0.f, 0.f, 0.f, 0.f};

    float wp0[4] = {0.f, 0.f, 0.f, 0.f};
    float wp1[4] = {0.f, 0.f, 0.f, 0.f};

    for (int T = 0; T < NTILE_LOC; ++T) {
        // ---- stage ----
        {
            int gs = sbase + T * TS + s0l;
            f16x4 hv[4];
            float ssqp[4] = {0.f, 0.f, 0.f, 0.f};
            float hdp[4]  = {0.f, 0.f, 0.f, 0.f};
            #pragma unroll
            for (int r = 0; r < 4; ++r) {
                const float* pr = xn + (size_t)(c0 + r) * S_ + gs;
                float f0, f1, f2, f3;
                if (gs + 3 < S_) {
                    f0 = pr[0]; f1 = pr[1]; f2 = pr[2]; f3 = pr[3];
                } else {
                    f0 = (gs + 0 < S_) ? pr[0] : 0.f;
                    f1 = (gs + 1 < S_) ? pr[1] : 0.f;
                    f2 = (gs + 2 < S_) ? pr[2] : 0.f;
                    f3 = (gs + 3 < S_) ? pr[3] : 0.f;
                }
                f16x4 v = {(_Float16)f0, (_Float16)f1, (_Float16)f2, (_Float16)f3};
                hv[r] = v;
                ssqp[0] += f0 * f0; ssqp[1] += f1 * f1;
                ssqp[2] += f2 * f2; ssqp[3] += f3 * f3;
                hdp[0] += fmaxf(f0, 0.f) * awr[r];
                hdp[1] += fmaxf(f1, 0.f) * awr[r];
                hdp[2] += fmaxf(f2, 0.f) * awr[r];
                hdp[3] += fmaxf(f3, 0.f) * awr[r];
                *(f16x4*)&s_xs[c0 + r][s0l] = v;
            }
            #pragma unroll
            for (int j = 0; j < 4; ++j) {
                int srow = s0l + j;
                int cidx = c0 ^ (((srow >> 3) & 3) << 3);
                f16x4 vT = {hv[0][j], hv[1][j], hv[2][j], hv[3][j]};
                *(f16x4*)&s_xT[srow][cidx] = vT;
            }
            #pragma unroll
            for (int j = 0; j < 4; ++j) {
                ssqp[j] += __shfl_xor(ssqp[j], 16);
                ssqp[j] += __shfl_xor(ssqp[j], 32);
                hdp[j]  += __shfl_xor(hdp[j], 16);
                hdp[j]  += __shfl_xor(hdp[j], 32);
            }
            if (lg == 0) {
                f32x4 a = {ssqp[0], ssqp[1], ssqp[2], ssqp[3]};
                f32x4 b = {hdp[0], hdp[1], hdp[2], hdp[3]};
                *(f32x4*)&s_ared[0][w][s0l] = a;
                *(f32x4*)&s_ared[1][w][s0l] = b;
            }
        }
        __syncthreads();  // A

        // ---- GEMM1 + alpha + exp + partial colsum ----
        float e0[4], e1[4], hm, al, csw;
        {
            int swz = ((sc >> 3) & 3) << 3;
            f32x4 d0 = {0.f, 0.f, 0.f, 0.f}, d1 = {0.f, 0.f, 0.f, 0.f};
            #pragma unroll
            for (int cc = 0; cc < 4; ++cc) {
                f16x8 a0 = *(const f16x8*)&s_cw[(mtb + 0) * 4 + cc][lane][0];
                f16x8 a1 = *(const f16x8*)&s_cw[(mtb + 1) * 4 + cc][lane][0];
                f16x8 b  = *(const f16x8*)&s_xT[sc][(8 * lg + 32 * cc) ^ swz];
                d0 = MFMAF(a0, b, d0);
                d1 = MFMAF(a1, b, d1);
            }
            float ssq = s_ared[0][2 * lg][sc] + s_ared[0][2 * lg + 1][sc];
            float hd  = s_ared[1][2 * lg][sc] + s_ared[1][2 * lg + 1][sc];
            ssq += __shfl_xor(ssq, 16); ssq += __shfl_xor(ssq, 32);
            hd  += __shfl_xor(hd, 16);  hd  += __shfl_xor(hd, 32);
            int sg = sbase + T * TS + sc;
            hm = (sg < S_) ? fmaxf(hd + bias, 0.f) : 0.f;
            al = hm / fmaxf(sqrtf(ssq), 1e-12f);
            float cs = 0.f;
            #pragma unroll
            for (int i = 0; i < 4; ++i) {
                e0[i] = __expf(d0[i] * al);
                e1[i] = __expf(d1[i] * al);
                cs += e0[i] + e1[i];
            }
            cs += __shfl_xor(cs, 16); cs += __shfl_xor(cs, 32);
            csw = cs;
            if (lg == 0) s_cs[w][sc] = cs;
        }
        __syncthreads();  // B

        // ---- softmax finish + u store ----
        {
            float cst = csw + s_cs[w ^ 4][sc];
            float wl = hm * __builtin_amdgcn_rcpf(cst);
            #pragma unroll
            for (int i = 0; i < 4; ++i) {
                float wv0 = e0[i] * wl;
                float wv1 = e1[i] * wl;
                wp0[i] += wv0;
                wp1[i] += wv1;
                s_u[16 * mtb + 4 * lg + i][sc]       = (_Float16)(wv0 * al);
                s_u[16 * (mtb + 1) + 4 * lg + i][sc] = (_Float16)(wv1 * al);
            }
        }
        __syncthreads();  // C

        // ---- GEMM2 ----
        {
            #pragma unroll
            for (int sc2 = 0; sc2 < 2; ++sc2) {
                f16x8 ua[2];
                #pragma unroll
                for (int m = 0; m < 2; ++m)
                    ua[m] = *(const f16x8*)&s_u[la + 16 * (mtb2 + m)][8 * lg + 32 * sc2];
                #pragma unroll
                for (int ci = 0; ci < 2; ++ci) {
                    f16x8 xb = *(const f16x8*)&s_xs[la + 16 * (ctb2 + ci)][8 * lg + 32 * sc2];
                    #pragma unroll
                    for (int m = 0; m < 2; ++m)
                        acc2[m][ci] = MFMAF(ua[m], xb, acc2[m][ci]);
                }
            }
        }
        __syncthreads();  // D
    }

    // ================= epilogue: wsum =================
    {
        #pragma unroll
        for (int i = 0; i < 4; ++i) {
            #pragma unroll
            for (int m = 1; m < 16; m <<= 1) {
                wp0[i] += __shfl_xor(wp0[i], m);
                wp1[i] += __shfl_xor(wp1[i], m);
            }
        }
        if (la == 0) {
            #pragma unroll
            for (int i = 0; i < 4; ++i) {
                s_wp[w][lg][i]     = wp0[i];
                s_wp[w][lg][4 + i] = wp1[i];
            }
        }
    }
    __syncthreads();
    if (tid < K_) {
        int k = tid;
        int kh = k >> 5, m2 = (k >> 4) & 1, lgk = (k >> 2) & 3, ik = k & 3;
        float v = 0.f;
        #pragma unroll
        for (int q = 0; q < 4; ++q) v += s_wp[4 * kh + q][lgk][4 * m2 + ik];
        s_wsum[k] = v;
    }
    __syncthreads();

    // ---- partial vlad with centroid folded (kept in registers) ----
    float val[2][2][4];
    #pragma unroll
    for (int m = 0; m < 2; ++m)
        #pragma unroll
        for (int ci = 0; ci < 2; ++ci) {
            int c = la + 16 * (ctb2 + ci);
            #pragma unroll
            for (int i = 0; i < 4; ++i) {
                int k = 16 * (mtb2 + m) + 4 * lg + i;
                val[m][ci][i] = acc2[m][ci][i] - cent[k * C_ + c] * s_wsum[k];
            }
        }

    if (MODE == 2) {
        #pragma unroll
        for (int m = 0; m < 2; ++m)
            #pragma unroll
            for (int ci = 0; ci < 2; ++ci) {
                int c = la + 16 * (ctb2 + ci);
                #pragma unroll
                for (int i = 0; i < 4; ++i) {
                    int k = 16 * (mtb2 + m) + 4 * lg + i;
                    atomicAdd(&out[(size_t)n * (K_ * C_) + k * C_ + c], val[m][ci][i]);
                }
            }
        return;
    }

    if (MODE == 0) {
        float* dst = (h ? ws : out) + (size_t)n * (K_ * C_);
        #pragma unroll
        for (int m = 0; m < 2; ++m)
            #pragma unroll
            for (int ci = 0; ci < 2; ++ci) {
                int c = la + 16 * (ctb2 + ci);
                #pragma unroll
                for (int i = 0; i < 4; ++i) {
                    int k = 16 * (mtb2 + m) + 4 * lg + i;
                    dst[k * C_ + c] = val[m][ci][i];
                }
            }
        return;
    }

    // ================= MODE 1: fused last-block finish =================
    {
        float* own = ws + (size_t)(2 * n + h) * (K_ * C_);
        #pragma unroll
        for (int m = 0; m < 2; ++m)
            #pragma unroll
            for (int ci = 0; ci < 2; ++ci) {
                int c = la + 16 * (ctb2 + ci);
                #pragma unroll
                for (int i = 0; i < 4; ++i) {
                    int k = 16 * (mtb2 + m) + 4 * lg + i;
                    own[k * C_ + c] = val[m][ci][i];
                }
            }
        __threadfence();   // release own partial device-wide
        __syncthreads();
        if (tid == 0) s_flag = atomicAdd(&cnt[n], 1);
        __syncthreads();
        if (s_flag != 1) return;   // first finisher exits

        __threadfence();   // acquire partner's partial
        const float* pp = ws + (size_t)(2 * n + (h ^ 1)) * (K_ * C_);
        #pragma unroll
        for (int m = 0; m < 2; ++m)
            #pragma unroll
            for (int ci = 0; ci < 2; ++ci) {
                int c = la + 16 * (ctb2 + ci);
                #pragma unroll
                for (int i = 0; i < 4; ++i) {
                    int k = 16 * (mtb2 + m) + 4 * lg + i;
                    val[m][ci][i] += pp[k * C_ + c];
                }
            }
        // per-k ssq: lane partial over ci, reduce over la (c dimension), stash per wave
        #pragma unroll
        for (int m = 0; m < 2; ++m) {
            #pragma unroll
            for (int i = 0; i < 4; ++i) {
                float s2 = val[m][0][i] * val[m][0][i] + val[m][1][i] * val[m][1][i];
                s2 += __shfl_xor(s2, 1);
                s2 += __shfl_xor(s2, 2);
                s2 += __shfl_xor(s2, 4);
                s2 += __shfl_xor(s2, 8);
                if (la == 0) s_ared[0][w][16 * (mtb2 + m) + 4 * lg + i] = s2;
            }
        }
        __syncthreads();
        if (tid < K_) {
            int k = tid;
            int p = k >> 5;   // parity: which w&1 owns this k-half
            float ssqk = s_ared[0][p][k] + s_ared[0][p + 2][k] +
                         s_ared[0][p + 4][k] + s_ared[0][p + 6][k];
            float rs = 1.0f / fmaxf(sqrtf(ssqk), 1e-12f);
            s_wsum[k] = rs;   // reuse as rs[k]
            float f = ssqk * rs * rs;
            #pragma unroll
            for (int mm = 1; mm < 64; mm <<= 1) f += __shfl_xor(f, mm);
            if (tid == 0) {
                float n1 = sqrtf(f);
                float sc1 = 1.0f / fmaxf(n1, 1e-12f);
                float n2 = n1 * sc1;
                float sc2 = 1.0f / fmaxf(n2, 1e-12f);
                s_fin = sc1 * sc2;
            }
        }
        __syncthreads();
        float fs = s_fin;
        float* on = out + (size_t)n * (K_ * C_);
        #pragma unroll
        for (int m = 0; m < 2; ++m)
            #pragma unroll
            for (int ci = 0; ci < 2; ++ci) {
                int c = la + 16 * (ctb2 + ci);
                #pragma unroll
                for (int i = 0; i < 4; ++i) {
                    int k = 16 * (mtb2 + m) + 4 * lg + i;
                    on[k * C_ + c] = val[m][ci][i] * s_wsum[k] * fs;
                }
            }
    }
}

template <bool WS>
__global__ __launch_bounds__(256) void vlad_norm(
    float* __restrict__ out, const float* __restrict__ ws)
{
    __shared__ float s_rs[K_], s_f[K_];
    __shared__ float s_fin;
    const int n = blockIdx.x, tid = threadIdx.x;
    const int k = tid >> 2, q = tid & 3;
    float* po = out + (size_t)n * (K_ * C_) + k * C_ + q * 32;
    const float* pw = ws + (size_t)n * (K_ * C_) + k * C_ + q * 32;

    float v[32];
    float ssq = 0.f;
    #pragma unroll
    for (int i = 0; i < 8; ++i) {
        f32x4 a = *(const f32x4*)&po[4 * i];
        if (WS) {
            f32x4 b = *(const f32x4*)&pw[4 * i];
            a[0]+=b[0]; a[1]+=b[1]; a[2]+=b[2]; a[3]+=b[3];
        }
        #pragma unroll
        for (int j = 0; j < 4; ++j) { v[4*i+j] = a[j]; ssq += a[j]*a[j]; }
    }
    ssq += __shfl_xor(ssq, 1);
    ssq += __shfl_xor(ssq, 2);
    if (q == 0) {
        float rs = 1.0f / fmaxf(sqrtf(ssq), 1e-12f);
        s_rs[k] = rs;
        s_f[k] = ssq * rs * rs;
    }
    __syncthreads();
    if (tid < 64) {
        float f = s_f[tid];
        #pragma unroll
        for (int m = 1; m < 64; m <<= 1) f += __shfl_xor(f, m);
        if (tid == 0) {
            float n1 = sqrtf(f);
            float sc1 = 1.0f / fmaxf(n1, 1e-12f);
            float n2 = n1 * sc1;
            float sc2 = 1.0f / fmaxf(n2, 1e-12f);
            s_fin = sc1 * sc2;
        }
    }
    __syncthreads();
    float sc = s_rs[k] * s_fin;
    #pragma unroll
    for (int i = 0; i < 8; ++i) {
        f32x4 a = {v[4*i]*sc, v[4*i+1]*sc, v[4*i+2]*sc, v[4*i+3]*sc};
        *(f32x4*)&po[4 * i] = a;
    }
}

extern "C" void kernel_launch(void* const* d_in, const int* in_sizes, int n_in,
                              void* d_out, int out_size, void* d_ws, size_t ws_size,
                              hipStream_t stream) {
    const float* x      = (const float*)d_in[0];
    const float* conv_w = (const float*)d_in[1];
    const float* cent   = (const float*)d_in[2];
    const float* aw     = (const float*)d_in[3];
    const float* ab     = (const float*)d_in[4];
    float* outp = (float*)d_out;
    float* wsp  = (float*)d_ws;

    const size_t part = (size_t)N_ * K_ * C_ * sizeof(float);       // 8 MB
    const size_t need_fused = 2 * part + N_ * sizeof(int);          // 16 MB + 1 KB

    if (ws_size >= need_fused) {
        int* cnt = (int*)((char*)d_ws + 2 * part);
        hipMemsetAsync(cnt, 0, N_ * sizeof(int), stream);
        vlad_main<1><<<2 * N_, NTHREADS, 0, stream>>>(x, conv_w, cent, aw, ab, outp, wsp, cnt);
    } else if (ws_size >= part) {
        vlad_main<0><<<2 * N_, NTHREADS, 0, stream>>>(x, conv_w, cent, aw, ab, outp, wsp, nullptr);
        vlad_norm<true><<<N_, 256, 0, stream>>>(outp, wsp);
    } else {
        hipMemsetAsync(d_out, 0, part, stream);
        vlad_main<2><<<2 * N_, NTHREADS, 0, stream>>>(x, conv_w, cent, aw, ab, outp, wsp, nullptr);
        vlad_norm<false><<<N_, 256, 0, stream>>>(outp, nullptr);
    }
}

// Round 14
// 76.913 us; speedup vs baseline: 3.3465x; 3.3465x over previous
//
#include <hip/hip_runtime.h>
#include <hip/hip_bf16.h>

#define N_ 256
#define C_ 128
#define S_ 961
#define K_ 64
#define TS 64
#define NTILE_LOC 8
#define NTHREADS 512

typedef __attribute__((ext_vector_type(4))) float f32x4;
typedef __attribute__((ext_vector_type(8))) _Float16 f16x8;
typedef __attribute__((ext_vector_type(4))) _Float16 f16x4;

#define MFMAF(a, b, c) __builtin_amdgcn_mfma_f32_16x16x32_f16((a), (b), (c), 0, 0, 0)

// MODE 0: partials to out/ws + separate norm kernel   MODE 2: atomicAdd into out
template <int MODE>
__global__ __launch_bounds__(NTHREADS, 8) void vlad_main(
    const float* __restrict__ x,       // [N,C,S]
    const float* __restrict__ conv_w,  // [K,C]
    const float* __restrict__ cent,    // [K,C]
    const float* __restrict__ aw,      // [C]
    const float* __restrict__ ab,      // [1]
    float* __restrict__ out,
    float* __restrict__ ws)
{
    __shared__ _Float16 s_xs[C_][64];      // [c][s^((c&7)<<3)] swizzled, pitch 128B
    __shared__ __align__(16) unsigned char s_xtu[TS * 128 * sizeof(_Float16)];
    _Float16 (*s_xT)[128] = (_Float16 (*)[128])s_xtu;  // [s][c^((s&7)<<3)], stage->GEMM1
    _Float16 (*s_u)[72]   = (_Float16 (*)[72])s_xtu;   // [k][s], softmax->GEMM2
    __shared__ _Float16 s_cw[16][64][8];   // conv_w fragments [mt*4+cc][lane][8]
    __shared__ float s_ared2[2][64];       // atomically-accumulated ssq/hd per col
    __shared__ float s_cs[8][18];          // per-wave partial colsums (by la)
    __shared__ float s_wp[8][4][8];
    __shared__ float s_wsum[K_];

    const int tid = threadIdx.x;
    const int bid = blockIdx.x;
    const int n = bid >> 1, h = bid & 1;
    const int sbase = h * (NTILE_LOC * TS);
    const int lane = tid & 63;
    const int w = tid >> 6;
    const int la = lane & 15;
    const int lg = lane >> 4;
    const float bias = ab[0];
    const float* xn = x + (size_t)n * (C_ * S_);

    const int cb = tid >> 4;
    const int c0 = cb * 4;
    const int s0l = (tid & 15) * 4;

    float awr[4];
    #pragma unroll
    for (int r = 0; r < 4; ++r) awr[r] = aw[c0 + r];

    // ---- stage conv_w fragments into LDS (once) ----
    {
        int b = tid >> 5;
        int mt = b >> 2, cc = b & 3;
        #pragma unroll
        for (int dl = 0; dl < 2; ++dl) {
            int l = (tid & 31) * 2 + dl;
            const float* p = conv_w + ((l & 15) + 16 * mt) * C_ + 8 * (l >> 4) + 32 * cc;
            f16x8 v;
            #pragma unroll
            for (int i = 0; i < 8; ++i) v[i] = (_Float16)p[i];
            *(f16x8*)&s_cw[b][l][0] = v;
        }
    }
    if (tid < 128) ((float*)s_ared2)[tid] = 0.f;
    __syncthreads();   // cw + ared2 ready

    const int nt1 = w & 3;
    const int mtb = (w >> 2) * 2;
    const int sc = 16 * nt1 + la;

    const int mtb2 = (w & 1) * 2;
    const int ctb2 = (w >> 1) * 2;
    f32x4 acc2[2][2];
    #pragma unroll
    for (int m = 0; m < 2; ++m)
        #pragma unroll
        for (int ci = 0; ci < 2; ++ci) acc2[m][ci] = (f32x4){0.f, 0.f, 0.f, 0.f};

    float wp0[4] = {0.f, 0.f, 0.f, 0.f};
    float wp1[4] = {0.f, 0.f, 0.f, 0.f};

    for (int T = 0; T < NTILE_LOC; ++T) {
        // ---- stage: global -> cvt -> swizzled LDS, alpha partials (atomic) ----
        {
            int gs = sbase + T * TS + s0l;
            f16x4 hv[4];
            float ssqp[4] = {0.f, 0.f, 0.f, 0.f};
            float hdp[4]  = {0.f, 0.f, 0.f, 0.f};
            #pragma unroll
            for (int r = 0; r < 4; ++r) {
                const float* pr = xn + (size_t)(c0 + r) * S_ + gs;
                float f0, f1, f2, f3;
                if (gs + 3 < S_) {
                    f0 = pr[0]; f1 = pr[1]; f2 = pr[2]; f3 = pr[3];
                } else {
                    f0 = (gs + 0 < S_) ? pr[0] : 0.f;
                    f1 = (gs + 1 < S_) ? pr[1] : 0.f;
                    f2 = (gs + 2 < S_) ? pr[2] : 0.f;
                    f3 = (gs + 3 < S_) ? pr[3] : 0.f;
                }
                f16x4 v = {(_Float16)f0, (_Float16)f1, (_Float16)f2, (_Float16)f3};
                hv[r] = v;
                ssqp[0] += f0 * f0; ssqp[1] += f1 * f1;
                ssqp[2] += f2 * f2; ssqp[3] += f3 * f3;
                hdp[0] += fmaxf(f0, 0.f) * awr[r];
                hdp[1] += fmaxf(f1, 0.f) * awr[r];
                hdp[2] += fmaxf(f2, 0.f) * awr[r];
                hdp[3] += fmaxf(f3, 0.f) * awr[r];
                int c = c0 + r;
                *(f16x4*)&s_xs[c][s0l ^ ((c & 7) << 3)] = v;
            }
            #pragma unroll
            for (int j = 0; j < 4; ++j) {
                int srow = s0l + j;
                int cidx = c0 ^ ((srow & 7) << 3);
                f16x4 vT = {hv[0][j], hv[1][j], hv[2][j], hv[3][j]};
                *(f16x4*)&s_xT[srow][cidx] = vT;
            }
            #pragma unroll
            for (int j = 0; j < 4; ++j) {
                ssqp[j] += __shfl_xor(ssqp[j], 16);
                ssqp[j] += __shfl_xor(ssqp[j], 32);
                hdp[j]  += __shfl_xor(hdp[j], 16);
                hdp[j]  += __shfl_xor(hdp[j], 32);
            }
            if (lg == 0) {
                #pragma unroll
                for (int j = 0; j < 4; ++j) {
                    atomicAdd(&s_ared2[0][s0l + j], ssqp[j]);
                    atomicAdd(&s_ared2[1][s0l + j], hdp[j]);
                }
            }
        }
        __syncthreads();  // A

        // ---- GEMM1 + alpha + exp + partial colsum ----
        float e0[4], e1[4], hm, al, csw;
        {
            int swz = (sc & 7) << 3;
            f32x4 d0 = {0.f, 0.f, 0.f, 0.f}, d1 = {0.f, 0.f, 0.f, 0.f};
            #pragma unroll
            for (int cc = 0; cc < 4; ++cc) {
                f16x8 a0 = *(const f16x8*)&s_cw[(mtb + 0) * 4 + cc][lane][0];
                f16x8 a1 = *(const f16x8*)&s_cw[(mtb + 1) * 4 + cc][lane][0];
                f16x8 b  = *(const f16x8*)&s_xT[sc][(8 * lg + 32 * cc) ^ swz];
                d0 = MFMAF(a0, b, d0);
                d1 = MFMAF(a1, b, d1);
            }
            float ssq = s_ared2[0][sc];
            float hd  = s_ared2[1][sc];
            int sg = sbase + T * TS + sc;
            hm = (sg < S_) ? fmaxf(hd + bias, 0.f) : 0.f;
            al = hm / fmaxf(sqrtf(ssq), 1e-12f);
            float cs = 0.f;
            #pragma unroll
            for (int i = 0; i < 4; ++i) {
                e0[i] = __expf(d0[i] * al);
                e1[i] = __expf(d1[i] * al);
                cs += e0[i] + e1[i];
            }
            cs += __shfl_xor(cs, 16); cs += __shfl_xor(cs, 32);
            csw = cs;
            if (lg == 0) s_cs[w][la] = cs;
        }
        __syncthreads();  // B

        // ---- softmax finish + u store; re-zero ared2 for next tile ----
        {
            if (tid < 128) ((float*)s_ared2)[tid] = 0.f;
            float cst = csw + s_cs[w ^ 4][la];
            float wl = hm * __builtin_amdgcn_rcpf(cst);
            #pragma unroll
            for (int i = 0; i < 4; ++i) {
                float wv0 = e0[i] * wl;
                float wv1 = e1[i] * wl;
                wp0[i] += wv0;
                wp1[i] += wv1;
                s_u[16 * mtb + 4 * lg + i][sc]       = (_Float16)(wv0 * al);
                s_u[16 * (mtb + 1) + 4 * lg + i][sc] = (_Float16)(wv1 * al);
            }
        }
        __syncthreads();  // C

        // ---- GEMM2 ----
        {
            #pragma unroll
            for (int sc2 = 0; sc2 < 2; ++sc2) {
                f16x8 ua[2];
                #pragma unroll
                for (int m = 0; m < 2; ++m)
                    ua[m] = *(const f16x8*)&s_u[la + 16 * (mtb2 + m)][8 * lg + 32 * sc2];
                #pragma unroll
                for (int ci = 0; ci < 2; ++ci) {
                    int c = la + 16 * (ctb2 + ci);
                    f16x8 xb = *(const f16x8*)&s_xs[c][(8 * lg + 32 * sc2) ^ ((c & 7) << 3)];
                    #pragma unroll
                    for (int m = 0; m < 2; ++m)
                        acc2[m][ci] = MFMAF(ua[m], xb, acc2[m][ci]);
                }
            }
        }
        __syncthreads();  // D
    }

    // ================= epilogue: wsum =================
    {
        #pragma unroll
        for (int i = 0; i < 4; ++i) {
            #pragma unroll
            for (int m = 1; m < 16; m <<= 1) {
                wp0[i] += __shfl_xor(wp0[i], m);
                wp1[i] += __shfl_xor(wp1[i], m);
            }
        }
        if (la == 0) {
            #pragma unroll
            for (int i = 0; i < 4; ++i) {
                s_wp[w][lg][i]     = wp0[i];
                s_wp[w][lg][4 + i] = wp1[i];
            }
        }
    }
    __syncthreads();
    if (tid < K_) {
        int k = tid;
        int kh = k >> 5, m2 = (k >> 4) & 1, lgk = (k >> 2) & 3, ik = k & 3;
        float v = 0.f;
        #pragma unroll
        for (int q = 0; q < 4; ++q) v += s_wp[4 * kh + q][lgk][4 * m2 + ik];
        s_wsum[k] = v;
    }
    __syncthreads();

    // ---- write partial vlad with centroid folded ----
    {
        #pragma unroll
        for (int m = 0; m < 2; ++m)
            #pragma unroll
            for (int ci = 0; ci < 2; ++ci) {
                int c = la + 16 * (ctb2 + ci);
                #pragma unroll
                for (int i = 0; i < 4; ++i) {
                    int k = 16 * (mtb2 + m) + 4 * lg + i;
                    float val = acc2[m][ci][i] - cent[k * C_ + c] * s_wsum[k];
                    size_t off = (size_t)n * (K_ * C_) + k * C_ + c;
                    if (MODE == 2) atomicAdd(&out[off], val);
                    else { float* dst = (h ? ws : out); dst[off] = val; }
                }
            }
    }
}

template <bool WS>
__global__ __launch_bounds__(256) void vlad_norm(
    float* __restrict__ out, const float* __restrict__ ws)
{
    __shared__ float s_rs[K_], s_f[K_];
    __shared__ float s_fin;
    const int n = blockIdx.x, tid = threadIdx.x;
    const int k = tid >> 2, q = tid & 3;
    float* po = out + (size_t)n * (K_ * C_) + k * C_ + q * 32;
    const float* pw = ws + (size_t)n * (K_ * C_) + k * C_ + q * 32;

    float v[32];
    float ssq = 0.f;
    #pragma unroll
    for (int i = 0; i < 8; ++i) {
        f32x4 a = *(const f32x4*)&po[4 * i];
        if (WS) {
            f32x4 b = *(const f32x4*)&pw[4 * i];
            a[0]+=b[0]; a[1]+=b[1]; a[2]+=b[2]; a[3]+=b[3];
        }
        #pragma unroll
        for (int j = 0; j < 4; ++j) { v[4*i+j] = a[j]; ssq += a[j]*a[j]; }
    }
    ssq += __shfl_xor(ssq, 1);
    ssq += __shfl_xor(ssq, 2);
    if (q == 0) {
        float rs = 1.0f / fmaxf(sqrtf(ssq), 1e-12f);
        s_rs[k] = rs;
        s_f[k] = ssq * rs * rs;
    }
    __syncthreads();
    if (tid < 64) {
        float f = s_f[tid];
        #pragma unroll
        for (int m = 1; m < 64; m <<= 1) f += __shfl_xor(f, m);
        if (tid == 0) {
            float n1 = sqrtf(f);
            float sc1 = 1.0f / fmaxf(n1, 1e-12f);
            float n2 = n1 * sc1;
            float sc2 = 1.0f / fmaxf(n2, 1e-12f);
            s_fin = sc1 * sc2;
        }
    }
    __syncthreads();
    float sc = s_rs[k] * s_fin;
    #pragma unroll
    for (int i = 0; i < 8; ++i) {
        f32x4 a = {v[4*i]*sc, v[4*i+1]*sc, v[4*i+2]*sc, v[4*i+3]*sc};
        *(f32x4*)&po[4 * i] = a;
    }
}

extern "C" void kernel_launch(void* const* d_in, const int* in_sizes, int n_in,
                              void* d_out, int out_size, void* d_ws, size_t ws_size,
                              hipStream_t stream) {
    const float* x      = (const float*)d_in[0];
    const float* conv_w = (const float*)d_in[1];
    const float* cent   = (const float*)d_in[2];
    const float* aw     = (const float*)d_in[3];
    const float* ab     = (const float*)d_in[4];
    float* outp = (float*)d_out;
    float* wsp  = (float*)d_ws;

    const size_t part = (size_t)N_ * K_ * C_ * sizeof(float);   // 8 MB

    if (ws_size >= part) {
        vlad_main<0><<<2 * N_, NTHREADS, 0, stream>>>(x, conv_w, cent, aw, ab, outp, wsp);
        vlad_norm<true><<<N_, 256, 0, stream>>>(outp, wsp);
    } else {
        hipMemsetAsync(d_out, 0, part, stream);
        vlad_main<2><<<2 * N_, NTHREADS, 0, stream>>>(x, conv_w, cent, aw, ab, outp, wsp);
        vlad_norm<false><<<N_, 256, 0, stream>>>(outp, nullptr);
    }
}

// Round 15
// 55.193 us; speedup vs baseline: 4.6634x; 1.3935x over previous
//
#include <hip/hip_runtime.h>
#include <hip/hip_bf16.h>

#define N_ 256
#define C_ 128
#define S_ 961
#define K_ 64
#define TS 64
#define NTILE_LOC 8
#define NTHREADS 512

typedef __attribute__((ext_vector_type(4))) float f32x4;
typedef __attribute__((ext_vector_type(8))) _Float16 f16x8;
typedef __attribute__((ext_vector_type(4))) _Float16 f16x4;

#define MFMAF(a, b, c) __builtin_amdgcn_mfma_f32_16x16x32_f16((a), (b), (c), 0, 0, 0)

// MODE 0: partials to out/ws + separate norm kernel   MODE 2: atomicAdd into out
template <int MODE>
__global__ __launch_bounds__(NTHREADS, 8) void vlad_main(
    const float* __restrict__ x,       // [N,C,S]
    const float* __restrict__ conv_w,  // [K,C]
    const float* __restrict__ cent,    // [K,C]
    const float* __restrict__ aw,      // [C]
    const float* __restrict__ ab,      // [1]
    float* __restrict__ out,
    float* __restrict__ ws)
{
    __shared__ _Float16 s_xs[C_][72];      // [c][s] pitch 144B
    // xT and u have disjoint live ranges within a tile -> union
    __shared__ __align__(16) unsigned char s_xtu[TS * 136 * sizeof(_Float16)];
    _Float16 (*s_xT)[136] = (_Float16 (*)[136])s_xtu;  // [s][c], stage->GEMM1
    _Float16 (*s_u)[72]   = (_Float16 (*)[72])s_xtu;   // [k][s], softmax->GEMM2
    __shared__ _Float16 s_cw[16][64][8];   // conv_w fragments [mt*4+cc][lane][8]
    __shared__ float s_ared[2][8][68];     // [ssq/hd][wave][s]
    __shared__ float s_cs[8][68];          // per-wave partial colsums
    __shared__ float s_wp[8][4][8];
    __shared__ float s_wsum[K_];

    const int tid = threadIdx.x;
    const int bid = blockIdx.x;
    const int n = bid >> 1, h = bid & 1;
    const int sbase = h * (NTILE_LOC * TS);
    const int lane = tid & 63;
    const int w = tid >> 6;
    const int la = lane & 15;
    const int lg = lane >> 4;
    const float bias = ab[0];
    const float* xn = x + (size_t)n * (C_ * S_);

    const int cb = tid >> 4;
    const int c0 = cb * 4;
    const int s0l = (tid & 15) * 4;

    float awr[4];
    #pragma unroll
    for (int r = 0; r < 4; ++r) awr[r] = aw[c0 + r];

    // ---- stage conv_w fragments into LDS (once) ----
    {
        int b = tid >> 5;
        int mt = b >> 2, cc = b & 3;
        #pragma unroll
        for (int dl = 0; dl < 2; ++dl) {
            int l = (tid & 31) * 2 + dl;
            const float* p = conv_w + ((l & 15) + 16 * mt) * C_ + 8 * (l >> 4) + 32 * cc;
            f16x8 v;
            #pragma unroll
            for (int i = 0; i < 8; ++i) v[i] = (_Float16)p[i];
            *(f16x8*)&s_cw[b][l][0] = v;
        }
    }

    const int nt1 = w & 3;
    const int mtb = (w >> 2) * 2;
    const int sc = 16 * nt1 + la;

    const int mtb2 = (w & 1) * 2;
    const int ctb2 = (w >> 1) * 2;
    f32x4 acc2[2][2];
    #pragma unroll
    for (int m = 0; m < 2; ++m)
        #pragma unroll
        for (int ci = 0; ci < 2; ++ci) acc2[m][ci] = (f32x4){0.f, 0.f, 0.f, 0.f};

    float wp0[4] = {0.f, 0.f, 0.f, 0.f};
    float wp1[4] = {0.f, 0.f, 0.f, 0.f};

    for (int T = 0; T < NTILE_LOC; ++T) {
        // ---- stage: global -> cvt -> LDS, alpha partials ----
        {
            int gs = sbase + T * TS + s0l;
            f16x4 hv[4];
            float ssqp[4] = {0.f, 0.f, 0.f, 0.f};
            float hdp[4]  = {0.f, 0.f, 0.f, 0.f};
            #pragma unroll
            for (int r = 0; r < 4; ++r) {
                const float* pr = xn + (size_t)(c0 + r) * S_ + gs;
                float f0, f1, f2, f3;
                if (gs + 3 < S_) {
                    f0 = pr[0]; f1 = pr[1]; f2 = pr[2]; f3 = pr[3];
                } else {
                    f0 = (gs + 0 < S_) ? pr[0] : 0.f;
                    f1 = (gs + 1 < S_) ? pr[1] : 0.f;
                    f2 = (gs + 2 < S_) ? pr[2] : 0.f;
                    f3 = (gs + 3 < S_) ? pr[3] : 0.f;
                }
                f16x4 v = {(_Float16)f0, (_Float16)f1, (_Float16)f2, (_Float16)f3};
                hv[r] = v;
                ssqp[0] += f0 * f0; ssqp[1] += f1 * f1;
                ssqp[2] += f2 * f2; ssqp[3] += f3 * f3;
                hdp[0] += fmaxf(f0, 0.f) * awr[r];
                hdp[1] += fmaxf(f1, 0.f) * awr[r];
                hdp[2] += fmaxf(f2, 0.f) * awr[r];
                hdp[3] += fmaxf(f3, 0.f) * awr[r];
                *(f16x4*)&s_xs[c0 + r][s0l] = v;
            }
            #pragma unroll
            for (int j = 0; j < 4; ++j) {
                int srow = s0l + j;
                int cidx = c0 ^ (((srow >> 3) & 3) << 3);
                f16x4 vT = {hv[0][j], hv[1][j], hv[2][j], hv[3][j]};
                *(f16x4*)&s_xT[srow][cidx] = vT;
            }
            #pragma unroll
            for (int j = 0; j < 4; ++j) {
                ssqp[j] += __shfl_xor(ssqp[j], 16);
                ssqp[j] += __shfl_xor(ssqp[j], 32);
                hdp[j]  += __shfl_xor(hdp[j], 16);
                hdp[j]  += __shfl_xor(hdp[j], 32);
            }
            if (lg == 0) {
                f32x4 a = {ssqp[0], ssqp[1], ssqp[2], ssqp[3]};
                f32x4 b = {hdp[0], hdp[1], hdp[2], hdp[3]};
                *(f32x4*)&s_ared[0][w][s0l] = a;
                *(f32x4*)&s_ared[1][w][s0l] = b;
            }
        }
        __syncthreads();  // A

        // ---- GEMM1 + alpha + exp + partial colsum ----
        float e0[4], e1[4], hm, al, csw;
        {
            int swz = ((sc >> 3) & 3) << 3;
            f32x4 d0 = {0.f, 0.f, 0.f, 0.f}, d1 = {0.f, 0.f, 0.f, 0.f};
            __builtin_amdgcn_s_setprio(1);
            #pragma unroll
            for (int cc = 0; cc < 4; ++cc) {
                f16x8 a0 = *(const f16x8*)&s_cw[(mtb + 0) * 4 + cc][lane][0];
                f16x8 a1 = *(const f16x8*)&s_cw[(mtb + 1) * 4 + cc][lane][0];
                f16x8 b  = *(const f16x8*)&s_xT[sc][(8 * lg + 32 * cc) ^ swz];
                d0 = MFMAF(a0, b, d0);
                d1 = MFMAF(a1, b, d1);
            }
            __builtin_amdgcn_s_setprio(0);
            float ssq = s_ared[0][2 * lg][sc] + s_ared[0][2 * lg + 1][sc];
            float hd  = s_ared[1][2 * lg][sc] + s_ared[1][2 * lg + 1][sc];
            ssq += __shfl_xor(ssq, 16); ssq += __shfl_xor(ssq, 32);
            hd  += __shfl_xor(hd, 16);  hd  += __shfl_xor(hd, 32);
            int sg = sbase + T * TS + sc;
            hm = (sg < S_) ? fmaxf(hd + bias, 0.f) : 0.f;
            al = hm / fmaxf(sqrtf(ssq), 1e-12f);
            float cs = 0.f;
            #pragma unroll
            for (int i = 0; i < 4; ++i) {
                e0[i] = __expf(d0[i] * al);
                e1[i] = __expf(d1[i] * al);
                cs += e0[i] + e1[i];
            }
            cs += __shfl_xor(cs, 16); cs += __shfl_xor(cs, 32);
            csw = cs;
            if (lg == 0) s_cs[w][sc] = cs;
        }
        __syncthreads();  // B

        // ---- softmax finish + u store ----
        {
            float cst = csw + s_cs[w ^ 4][sc];
            float wl = hm * __builtin_amdgcn_rcpf(cst);
            #pragma unroll
            for (int i = 0; i < 4; ++i) {
                float wv0 = e0[i] * wl;
                float wv1 = e1[i] * wl;
                wp0[i] += wv0;
                wp1[i] += wv1;
                s_u[16 * mtb + 4 * lg + i][sc]       = (_Float16)(wv0 * al);
                s_u[16 * (mtb + 1) + 4 * lg + i][sc] = (_Float16)(wv1 * al);
            }
        }
        __syncthreads();  // C

        // ---- GEMM2 ----
        {
            __builtin_amdgcn_s_setprio(1);
            #pragma unroll
            for (int sc2 = 0; sc2 < 2; ++sc2) {
                f16x8 ua[2];
                #pragma unroll
                for (int m = 0; m < 2; ++m)
                    ua[m] = *(const f16x8*)&s_u[la + 16 * (mtb2 + m)][8 * lg + 32 * sc2];
                #pragma unroll
                for (int ci = 0; ci < 2; ++ci) {
                    f16x8 xb = *(const f16x8*)&s_xs[la + 16 * (ctb2 + ci)][8 * lg + 32 * sc2];
                    #pragma unroll
                    for (int m = 0; m < 2; ++m)
                        acc2[m][ci] = MFMAF(ua[m], xb, acc2[m][ci]);
                }
            }
            __builtin_amdgcn_s_setprio(0);
        }
        __syncthreads();  // D
    }

    // ================= epilogue: wsum =================
    {
        #pragma unroll
        for (int i = 0; i < 4; ++i) {
            #pragma unroll
            for (int m = 1; m < 16; m <<= 1) {
                wp0[i] += __shfl_xor(wp0[i], m);
                wp1[i] += __shfl_xor(wp1[i], m);
            }
        }
        if (la == 0) {
            #pragma unroll
            for (int i = 0; i < 4; ++i) {
                s_wp[w][lg][i]     = wp0[i];
                s_wp[w][lg][4 + i] = wp1[i];
            }
        }
    }
    __syncthreads();
    if (tid < K_) {
        int k = tid;
        int kh = k >> 5, m2 = (k >> 4) & 1, lgk = (k >> 2) & 3, ik = k & 3;
        float v = 0.f;
        #pragma unroll
        for (int q = 0; q < 4; ++q) v += s_wp[4 * kh + q][lgk][4 * m2 + ik];
        s_wsum[k] = v;
    }
    __syncthreads();

    // ---- write partial vlad with centroid folded ----
    {
        #pragma unroll
        for (int m = 0; m < 2; ++m)
            #pragma unroll
            for (int ci = 0; ci < 2; ++ci) {
                int c = la + 16 * (ctb2 + ci);
                #pragma unroll
                for (int i = 0; i < 4; ++i) {
                    int k = 16 * (mtb2 + m) + 4 * lg + i;
                    float val = acc2[m][ci][i] - cent[k * C_ + c] * s_wsum[k];
                    size_t off = (size_t)n * (K_ * C_) + k * C_ + c;
                    if (MODE == 2) atomicAdd(&out[off], val);
                    else { float* dst = (h ? ws : out); dst[off] = val; }
                }
            }
    }
}

template <bool WS>
__global__ __launch_bounds__(256) void vlad_norm(
    float* __restrict__ out, const float* __restrict__ ws)
{
    __shared__ float s_rs[K_], s_f[K_];
    __shared__ float s_fin;
    const int n = blockIdx.x, tid = threadIdx.x;
    const int k = tid >> 2, q = tid & 3;
    float* po = out + (size_t)n * (K_ * C_) + k * C_ + q * 32;
    const float* pw = ws + (size_t)n * (K_ * C_) + k * C_ + q * 32;

    float v[32];
    float ssq = 0.f;
    #pragma unroll
    for (int i = 0; i < 8; ++i) {
        f32x4 a = *(const f32x4*)&po[4 * i];
        if (WS) {
            f32x4 b = *(const f32x4*)&pw[4 * i];
            a[0]+=b[0]; a[1]+=b[1]; a[2]+=b[2]; a[3]+=b[3];
        }
        #pragma unroll
        for (int j = 0; j < 4; ++j) { v[4*i+j] = a[j]; ssq += a[j]*a[j]; }
    }
    ssq += __shfl_xor(ssq, 1);
    ssq += __shfl_xor(ssq, 2);
    if (q == 0) {
        float rs = 1.0f / fmaxf(sqrtf(ssq), 1e-12f);
        s_rs[k] = rs;
        s_f[k] = ssq * rs * rs;
    }
    __syncthreads();
    if (tid < 64) {
        float f = s_f[tid];
        #pragma unroll
        for (int m = 1; m < 64; m <<= 1) f += __shfl_xor(f, m);
        if (tid == 0) {
            float n1 = sqrtf(f);
            float sc1 = 1.0f / fmaxf(n1, 1e-12f);
            float n2 = n1 * sc1;
            float sc2 = 1.0f / fmaxf(n2, 1e-12f);
            s_fin = sc1 * sc2;
        }
    }
    __syncthreads();
    float sc = s_rs[k] * s_fin;
    #pragma unroll
    for (int i = 0; i < 8; ++i) {
        f32x4 a = {v[4*i]*sc, v[4*i+1]*sc, v[4*i+2]*sc, v[4*i+3]*sc};
        *(f32x4*)&po[4 * i] = a;
    }
}

extern "C" void kernel_launch(void* const* d_in, const int* in_sizes, int n_in,
                              void* d_out, int out_size, void* d_ws, size_t ws_size,
                              hipStream_t stream) {
    const float* x      = (const float*)d_in[0];
    const float* conv_w = (const float*)d_in[1];
    const float* cent   = (const float*)d_in[2];
    const float* aw     = (const float*)d_in[3];
    const float* ab     = (const float*)d_in[4];
    float* outp = (float*)d_out;
    float* wsp  = (float*)d_ws;

    const size_t part = (size_t)N_ * K_ * C_ * sizeof(float);   // 8 MB

    if (ws_size >= part) {
        vlad_main<0><<<2 * N_, NTHREADS, 0, stream>>>(x, conv_w, cent, aw, ab, outp, wsp);
        vlad_norm<true><<<N_, 256, 0, stream>>>(outp, wsp);
    } else {
        hipMemsetAsync(d_out, 0, part, stream);
        vlad_main<2><<<2 * N_, NTHREADS, 0, stream>>>(x, conv_w, cent, aw, ab, outp, wsp);
        vlad_norm<false><<<N_, 256, 0, stream>>>(outp, nullptr);
    }
}

// Round 16
// 53.062 us; speedup vs baseline: 4.8507x; 1.0402x over previous
//
#include <hip/hip_runtime.h>
#include <hip/hip_bf16.h>

#define N_ 256
#define C_ 128
#define S_ 961
#define K_ 64
#define TS 64
#define NTILE_LOC 8
#define NTHREADS 512

typedef __attribute__((ext_vector_type(4))) float f32x4;
typedef __attribute__((ext_vector_type(8))) _Float16 f16x8;
typedef __attribute__((ext_vector_type(4))) _Float16 f16x4;

#define MFMAF(a, b, c) __builtin_amdgcn_mfma_f32_16x16x32_f16((a), (b), (c), 0, 0, 0)

// MODE 0: fp16 partials to ws + combine-norm kernel   MODE 2: atomicAdd into out + norm
template <int MODE>
__global__ __launch_bounds__(NTHREADS, 8) void vlad_main(
    const float* __restrict__ x,       // [N,C,S]
    const float* __restrict__ conv_w,  // [K,C]
    const float* __restrict__ cent,    // [K,C]
    const float* __restrict__ aw,      // [C]
    const float* __restrict__ ab,      // [1]
    float* __restrict__ out,
    _Float16* __restrict__ ws)         // [2N][K*C] fp16 partials
{
    __shared__ _Float16 s_xs[C_][72];      // [c][s] pitch 144B
    // xT and u have disjoint live ranges within a tile -> union
    __shared__ __align__(16) unsigned char s_xtu[TS * 136 * sizeof(_Float16)];
    _Float16 (*s_xT)[136] = (_Float16 (*)[136])s_xtu;  // [s][c], stage->GEMM1
    _Float16 (*s_u)[72]   = (_Float16 (*)[72])s_xtu;   // [k][s], softmax->GEMM2
    __shared__ _Float16 s_cw[16][64][8];   // conv_w fragments [mt*4+cc][lane][8]
    __shared__ float s_ared[2][8][68];     // [ssq/hd][wave][s]
    __shared__ float s_cs[8][68];          // per-wave partial colsums
    __shared__ float s_wp[8][4][8];
    __shared__ float s_wsum[K_];

    const int tid = threadIdx.x;
    const int bid = blockIdx.x;
    const int n = bid >> 1, h = bid & 1;
    const int sbase = h * (NTILE_LOC * TS);
    const int lane = tid & 63;
    const int w = tid >> 6;
    const int la = lane & 15;
    const int lg = lane >> 4;
    const float bias = ab[0];
    const float* xn = x + (size_t)n * (C_ * S_);

    const int cb = tid >> 4;
    const int c0 = cb * 4;
    const int s0l = (tid & 15) * 4;

    float awr[4];
    #pragma unroll
    for (int r = 0; r < 4; ++r) awr[r] = aw[c0 + r];

    // ---- stage conv_w fragments into LDS (once) ----
    {
        int b = tid >> 5;
        int mt = b >> 2, cc = b & 3;
        #pragma unroll
        for (int dl = 0; dl < 2; ++dl) {
            int l = (tid & 31) * 2 + dl;
            const float* p = conv_w + ((l & 15) + 16 * mt) * C_ + 8 * (l >> 4) + 32 * cc;
            f16x8 v;
            #pragma unroll
            for (int i = 0; i < 8; ++i) v[i] = (_Float16)p[i];
            *(f16x8*)&s_cw[b][l][0] = v;
        }
    }

    const int nt1 = w & 3;
    const int mtb = (w >> 2) * 2;
    const int sc = 16 * nt1 + la;

    const int mtb2 = (w & 1) * 2;
    const int ctb2 = (w >> 1) * 2;
    f32x4 acc2[2][2];
    #pragma unroll
    for (int m = 0; m < 2; ++m)
        #pragma unroll
        for (int ci = 0; ci < 2; ++ci) acc2[m][ci] = (f32x4){0.f, 0.f, 0.f, 0.f};

    float wp0[4] = {0.f, 0.f, 0.f, 0.f};
    float wp1[4] = {0.f, 0.f, 0.f, 0.f};

    for (int T = 0; T < NTILE_LOC; ++T) {
        // ---- stage: global -> cvt -> LDS, alpha partials ----
        {
            int gs = sbase + T * TS + s0l;
            f16x4 hv[4];
            float ssqp[4] = {0.f, 0.f, 0.f, 0.f};
            float hdp[4]  = {0.f, 0.f, 0.f, 0.f};
            #pragma unroll
            for (int r = 0; r < 4; ++r) {
                const float* pr = xn + (size_t)(c0 + r) * S_ + gs;
                float f0, f1, f2, f3;
                if (gs + 3 < S_) {
                    f0 = pr[0]; f1 = pr[1]; f2 = pr[2]; f3 = pr[3];
                } else {
                    f0 = (gs + 0 < S_) ? pr[0] : 0.f;
                    f1 = (gs + 1 < S_) ? pr[1] : 0.f;
                    f2 = (gs + 2 < S_) ? pr[2] : 0.f;
                    f3 = (gs + 3 < S_) ? pr[3] : 0.f;
                }
                f16x4 v = {(_Float16)f0, (_Float16)f1, (_Float16)f2, (_Float16)f3};
                hv[r] = v;
                ssqp[0] += f0 * f0; ssqp[1] += f1 * f1;
                ssqp[2] += f2 * f2; ssqp[3] += f3 * f3;
                hdp[0] += fmaxf(f0, 0.f) * awr[r];
                hdp[1] += fmaxf(f1, 0.f) * awr[r];
                hdp[2] += fmaxf(f2, 0.f) * awr[r];
                hdp[3] += fmaxf(f3, 0.f) * awr[r];
                *(f16x4*)&s_xs[c0 + r][s0l] = v;
            }
            #pragma unroll
            for (int j = 0; j < 4; ++j) {
                int srow = s0l + j;
                int cidx = c0 ^ (((srow >> 3) & 3) << 3);
                f16x4 vT = {hv[0][j], hv[1][j], hv[2][j], hv[3][j]};
                *(f16x4*)&s_xT[srow][cidx] = vT;
            }
            #pragma unroll
            for (int j = 0; j < 4; ++j) {
                ssqp[j] += __shfl_xor(ssqp[j], 16);
                ssqp[j] += __shfl_xor(ssqp[j], 32);
                hdp[j]  += __shfl_xor(hdp[j], 16);
                hdp[j]  += __shfl_xor(hdp[j], 32);
            }
            if (lg == 0) {
                f32x4 a = {ssqp[0], ssqp[1], ssqp[2], ssqp[3]};
                f32x4 b = {hdp[0], hdp[1], hdp[2], hdp[3]};
                *(f32x4*)&s_ared[0][w][s0l] = a;
                *(f32x4*)&s_ared[1][w][s0l] = b;
            }
        }
        __syncthreads();  // A

        // ---- GEMM1 + alpha + exp + partial colsum ----
        float e0[4], e1[4], hm, al, csw;
        {
            int swz = ((sc >> 3) & 3) << 3;
            f32x4 d0 = {0.f, 0.f, 0.f, 0.f}, d1 = {0.f, 0.f, 0.f, 0.f};
            __builtin_amdgcn_s_setprio(1);
            #pragma unroll
            for (int cc = 0; cc < 4; ++cc) {
                f16x8 a0 = *(const f16x8*)&s_cw[(mtb + 0) * 4 + cc][lane][0];
                f16x8 a1 = *(const f16x8*)&s_cw[(mtb + 1) * 4 + cc][lane][0];
                f16x8 b  = *(const f16x8*)&s_xT[sc][(8 * lg + 32 * cc) ^ swz];
                d0 = MFMAF(a0, b, d0);
                d1 = MFMAF(a1, b, d1);
            }
            __builtin_amdgcn_s_setprio(0);
            float ssq = s_ared[0][2 * lg][sc] + s_ared[0][2 * lg + 1][sc];
            float hd  = s_ared[1][2 * lg][sc] + s_ared[1][2 * lg + 1][sc];
            ssq += __shfl_xor(ssq, 16); ssq += __shfl_xor(ssq, 32);
            hd  += __shfl_xor(hd, 16);  hd  += __shfl_xor(hd, 32);
            int sg = sbase + T * TS + sc;
            hm = (sg < S_) ? fmaxf(hd + bias, 0.f) : 0.f;
            al = hm / fmaxf(sqrtf(ssq), 1e-12f);
            float cs = 0.f;
            #pragma unroll
            for (int i = 0; i < 4; ++i) {
                e0[i] = __expf(d0[i] * al);
                e1[i] = __expf(d1[i] * al);
                cs += e0[i] + e1[i];
            }
            cs += __shfl_xor(cs, 16); cs += __shfl_xor(cs, 32);
            csw = cs;
            if (lg == 0) s_cs[w][sc] = cs;
        }
        __syncthreads();  // B

        // ---- softmax finish + u store ----
        {
            float cst = csw + s_cs[w ^ 4][sc];
            float wl = hm * __builtin_amdgcn_rcpf(cst);
            #pragma unroll
            for (int i = 0; i < 4; ++i) {
                float wv0 = e0[i] * wl;
                float wv1 = e1[i] * wl;
                wp0[i] += wv0;
                wp1[i] += wv1;
                s_u[16 * mtb + 4 * lg + i][sc]       = (_Float16)(wv0 * al);
                s_u[16 * (mtb + 1) + 4 * lg + i][sc] = (_Float16)(wv1 * al);
            }
        }
        __syncthreads();  // C

        // ---- GEMM2 ----
        {
            __builtin_amdgcn_s_setprio(1);
            #pragma unroll
            for (int sc2 = 0; sc2 < 2; ++sc2) {
                f16x8 ua[2];
                #pragma unroll
                for (int m = 0; m < 2; ++m)
                    ua[m] = *(const f16x8*)&s_u[la + 16 * (mtb2 + m)][8 * lg + 32 * sc2];
                #pragma unroll
                for (int ci = 0; ci < 2; ++ci) {
                    f16x8 xb = *(const f16x8*)&s_xs[la + 16 * (ctb2 + ci)][8 * lg + 32 * sc2];
                    #pragma unroll
                    for (int m = 0; m < 2; ++m)
                        acc2[m][ci] = MFMAF(ua[m], xb, acc2[m][ci]);
                }
            }
            __builtin_amdgcn_s_setprio(0);
        }
        __syncthreads();  // D
    }

    // ================= epilogue: wsum =================
    {
        #pragma unroll
        for (int i = 0; i < 4; ++i) {
            #pragma unroll
            for (int m = 1; m < 16; m <<= 1) {
                wp0[i] += __shfl_xor(wp0[i], m);
                wp1[i] += __shfl_xor(wp1[i], m);
            }
        }
        if (la == 0) {
            #pragma unroll
            for (int i = 0; i < 4; ++i) {
                s_wp[w][lg][i]     = wp0[i];
                s_wp[w][lg][4 + i] = wp1[i];
            }
        }
    }
    __syncthreads();
    if (tid < K_) {
        int k = tid;
        int kh = k >> 5, m2 = (k >> 4) & 1, lgk = (k >> 2) & 3, ik = k & 3;
        float v = 0.f;
        #pragma unroll
        for (int q = 0; q < 4; ++q) v += s_wp[4 * kh + q][lgk][4 * m2 + ik];
        s_wsum[k] = v;
    }
    __syncthreads();

    // ---- write partial vlad with centroid folded ----
    {
        #pragma unroll
        for (int m = 0; m < 2; ++m)
            #pragma unroll
            for (int ci = 0; ci < 2; ++ci) {
                int c = la + 16 * (ctb2 + ci);
                #pragma unroll
                for (int i = 0; i < 4; ++i) {
                    int k = 16 * (mtb2 + m) + 4 * lg + i;
                    float val = acc2[m][ci][i] - cent[k * C_ + c] * s_wsum[k];
                    if (MODE == 2) {
                        atomicAdd(&out[(size_t)n * (K_ * C_) + k * C_ + c], val);
                    } else {
                        ws[(size_t)(2 * n + h) * (K_ * C_) + k * C_ + c] = (_Float16)val;
                    }
                }
            }
    }
}

// combine fp16 partials + per-cluster norm + double flat norm
__global__ __launch_bounds__(256) void vlad_norm_h(
    float* __restrict__ out, const _Float16* __restrict__ ws)
{
    __shared__ float s_rs[K_], s_f[K_];
    __shared__ float s_fin;
    const int n = blockIdx.x, tid = threadIdx.x;
    const int k = tid >> 2, q = tid & 3;
    const size_t base = (size_t)k * C_ + q * 32;
    const _Float16* p0 = ws + (size_t)(2 * n) * (K_ * C_) + base;
    const _Float16* p1 = ws + (size_t)(2 * n + 1) * (K_ * C_) + base;
    float* po = out + (size_t)n * (K_ * C_) + base;

    float v[32];
    float ssq = 0.f;
    #pragma unroll
    for (int i = 0; i < 4; ++i) {
        f16x8 a = *(const f16x8*)&p0[8 * i];
        f16x8 b = *(const f16x8*)&p1[8 * i];
        #pragma unroll
        for (int j = 0; j < 8; ++j) {
            float s = (float)a[j] + (float)b[j];
            v[8 * i + j] = s;
            ssq += s * s;
        }
    }
    ssq += __shfl_xor(ssq, 1);
    ssq += __shfl_xor(ssq, 2);
    if (q == 0) {
        float rs = 1.0f / fmaxf(sqrtf(ssq), 1e-12f);
        s_rs[k] = rs;
        s_f[k] = ssq * rs * rs;
    }
    __syncthreads();
    if (tid < 64) {
        float f = s_f[tid];
        #pragma unroll
        for (int m = 1; m < 64; m <<= 1) f += __shfl_xor(f, m);
        if (tid == 0) {
            float n1 = sqrtf(f);
            float sc1 = 1.0f / fmaxf(n1, 1e-12f);
            float n2 = n1 * sc1;
            float sc2 = 1.0f / fmaxf(n2, 1e-12f);
            s_fin = sc1 * sc2;
        }
    }
    __syncthreads();
    float sc = s_rs[k] * s_fin;
    #pragma unroll
    for (int i = 0; i < 8; ++i) {
        f32x4 a = {v[4*i]*sc, v[4*i+1]*sc, v[4*i+2]*sc, v[4*i+3]*sc};
        *(f32x4*)&po[4 * i] = a;
    }
}

// fallback norm (in-place on fp32 out)
__global__ __launch_bounds__(256) void vlad_norm_f(float* __restrict__ out)
{
    __shared__ float s_rs[K_], s_f[K_];
    __shared__ float s_fin;
    const int n = blockIdx.x, tid = threadIdx.x;
    const int k = tid >> 2, q = tid & 3;
    float* po = out + (size_t)n * (K_ * C_) + k * C_ + q * 32;

    float v[32];
    float ssq = 0.f;
    #pragma unroll
    for (int i = 0; i < 8; ++i) {
        f32x4 a = *(const f32x4*)&po[4 * i];
        #pragma unroll
        for (int j = 0; j < 4; ++j) { v[4*i+j] = a[j]; ssq += a[j]*a[j]; }
    }
    ssq += __shfl_xor(ssq, 1);
    ssq += __shfl_xor(ssq, 2);
    if (q == 0) {
        float rs = 1.0f / fmaxf(sqrtf(ssq), 1e-12f);
        s_rs[k] = rs;
        s_f[k] = ssq * rs * rs;
    }
    __syncthreads();
    if (tid < 64) {
        float f = s_f[tid];
        #pragma unroll
        for (int m = 1; m < 64; m <<= 1) f += __shfl_xor(f, m);
        if (tid == 0) {
            float n1 = sqrtf(f);
            float sc1 = 1.0f / fmaxf(n1, 1e-12f);
            float n2 = n1 * sc1;
            float sc2 = 1.0f / fmaxf(n2, 1e-12f);
            s_fin = sc1 * sc2;
        }
    }
    __syncthreads();
    float sc = s_rs[k] * s_fin;
    #pragma unroll
    for (int i = 0; i < 8; ++i) {
        f32x4 a = {v[4*i]*sc, v[4*i+1]*sc, v[4*i+2]*sc, v[4*i+3]*sc};
        *(f32x4*)&po[4 * i] = a;
    }
}

extern "C" void kernel_launch(void* const* d_in, const int* in_sizes, int n_in,
                              void* d_out, int out_size, void* d_ws, size_t ws_size,
                              hipStream_t stream) {
    const float* x      = (const float*)d_in[0];
    const float* conv_w = (const float*)d_in[1];
    const float* cent   = (const float*)d_in[2];
    const float* aw     = (const float*)d_in[3];
    const float* ab     = (const float*)d_in[4];
    float* outp = (float*)d_out;
    _Float16* wsp = (_Float16*)d_ws;

    const size_t need = (size_t)2 * N_ * K_ * C_ * sizeof(_Float16);   // 8 MB

    if (ws_size >= need) {
        vlad_main<0><<<2 * N_, NTHREADS, 0, stream>>>(x, conv_w, cent, aw, ab, outp, wsp);
        vlad_norm_h<<<N_, 256, 0, stream>>>(outp, wsp);
    } else {
        hipMemsetAsync(d_out, 0, (size_t)N_ * K_ * C_ * sizeof(float), stream);
        vlad_main<2><<<2 * N_, NTHREADS, 0, stream>>>(x, conv_w, cent, aw, ab, outp, wsp);
        vlad_norm_f<<<N_, 256, 0, stream>>>(outp);
    }
}